// Round 12
// baseline (223.742 us; speedup 1.0000x reference)
//
#include <hip/hip_runtime.h>
#include <hip/hip_bf16.h>

#define NCLS   100000
#define NPAD   100096   // 782 * 128
#define BATCH  1024
#define EDIM   512

#define COS_M_  0.8775825618903728f
#define SIN_M_  0.479425538604203f
#define TH_     (-0.8775825618903728f)
#define MM_     0.2397127693021015f
#define SCALE_  64.0f

typedef __attribute__((ext_vector_type(8))) short short8;
typedef __attribute__((ext_vector_type(4))) float f32x4;

__device__ __forceinline__ ushort f2bf(float f) {
    // round-to-nearest-even f32 -> bf16
    uint u = __float_as_uint(f);
    u += 0x7fffu + ((u >> 16) & 1u);
    return (ushort)(u >> 16);
}

// One 64-lane wave per row: L2-normalize 512 f32 -> 512 bf16.
// Handles BOTH inputs in one launch: global wave id gw < BATCH -> emb row,
// else W row gw-BATCH (rows >= NCLS zero-filled for N-padding).
__global__ __launch_bounds__(256) void norm_all_kernel(
    const float* __restrict__ emb, const float* __restrict__ wgt,
    ushort* __restrict__ Ebf, ushort* __restrict__ Wbf)
{
    int gw   = (int)((blockIdx.x * blockDim.x + threadIdx.x) >> 6);
    int lane = (int)(threadIdx.x & 63);
    const float* ip;
    ushort* op;
    if (gw < BATCH) {
        ip = emb + (size_t)gw * EDIM + lane * 8;
        op = Ebf + (size_t)gw * EDIM + lane * 8;
    } else {
        int wr = gw - BATCH;
        if (wr >= NPAD) return;
        op = Wbf + (size_t)wr * EDIM + lane * 8;
        if (wr >= NCLS) {
            uint4 z = make_uint4(0u, 0u, 0u, 0u);
            *(uint4*)op = z;
            return;
        }
        ip = wgt + (size_t)wr * EDIM + lane * 8;
    }
    float4 x0 = *(const float4*)ip;
    float4 x1 = *(const float4*)(ip + 4);
    float ss = x0.x*x0.x + x0.y*x0.y + x0.z*x0.z + x0.w*x0.w
             + x1.x*x1.x + x1.y*x1.y + x1.z*x1.z + x1.w*x1.w;
    #pragma unroll
    for (int off = 32; off; off >>= 1) ss += __shfl_xor(ss, off, 64);
    float inv = 1.0f / fmaxf(sqrtf(ss), 1e-12f);
    uint w0 = (uint)f2bf(x0.x*inv) | ((uint)f2bf(x0.y*inv) << 16);
    uint w1 = (uint)f2bf(x0.z*inv) | ((uint)f2bf(x0.w*inv) << 16);
    uint w2 = (uint)f2bf(x1.x*inv) | ((uint)f2bf(x1.y*inv) << 16);
    uint w3 = (uint)f2bf(x1.z*inv) | ((uint)f2bf(x1.w*inv) << 16);
    uint4 r; r.x = w0; r.y = w1; r.z = w2; r.w = w3;
    *(uint4*)op = r;
}

#define GLL16(g, s) __builtin_amdgcn_global_load_lds(                    \
    (const __attribute__((address_space(1))) void*)(g),                  \
    (__attribute__((address_space(3))) void*)(s), 16, 0, 0)

// 128x128 tile, BK=32, 4 waves (2x2), mfma_f32_16x16x32_bf16 (SWAPPED
// operands: lane's 4 acc regs = 4 consecutive N-cols -> dwordx4 NT stores;
// NT essential: plain stores let the 400MB C stream evict B panels from L2,
// +64us measured R10). ASYMMETRIC pipeline: A double-buffered (1-step lead,
// L2-resident 1MB), B triple-buffered (2-step lead covers L3/HBM latency on
// the 102MB stream). LDS 40KB -> 4 blocks/CU (full TLP). Counted vmcnt(6)
// steady state: B(kt+1), B(kt+2), A(kt+1) stay in flight across barriers.
// XOR-swizzled K-slots, T1 XCD chunk swizzle. Margin fused into epilogue
// (rare branch, one label column per row).
__global__ __launch_bounds__(256, 4) void gemm_arc_kernel(
    const ushort* __restrict__ A,
    const ushort* __restrict__ B,
    const int* __restrict__ labels,
    float* __restrict__ C)
{
    __shared__ __align__(16) ushort Als[2][128 * 32];   // 16 KB
    __shared__ __align__(16) ushort Bls[3][128 * 32];   // 24 KB

    const int t    = (int)threadIdx.x;
    const int lane = t & 63;
    const int w    = t >> 6;
    const int wrow = w >> 1, wcol = w & 1;
    const int lr   = lane & 15, lg = lane >> 4;

    // T1 bijective XCD swizzle: the 8 M-blocks sharing a B-tile land on ONE
    // XCD. nwg = 6256, %8 == 0.
    const int nwg  = (int)gridDim.x;
    const int cpx  = nwg >> 3;               // 782
    const int bid  = (int)blockIdx.x;
    const int swz  = (bid & 7) * cpx + (bid >> 3);
    const int brow = swz & 7;                // M-tile (0..7)
    const int bcol = swz >> 3;               // N-tile (0..781)

    const f32x4 z4 = {0.f, 0.f, 0.f, 0.f};
    f32x4 acc[4][4];
    #pragma unroll
    for (int i = 0; i < 4; ++i)
        #pragma unroll
        for (int j = 0; j < 4; ++j) acc[i][j] = z4;

    // staging: 256 threads x 16 B = 4 KB per instruction = 64 rows x 64 B.
    // LDS dest linear; global SOURCE byte offset carries the inverse K-slot
    // swizzle off' ^= ((row>>1)&3)<<4.
    const int srow = t >> 2;
    const int scb  = ((t & 3) * 16) ^ (((t >> 3) & 3) << 4);
    const char* Ab = (const char*)(A + ((size_t)brow * 128 + srow) * EDIM) + scb;
    const char* Bb = (const char*)(B + ((size_t)bcol * 128 + srow) * EDIM) + scb;
    const uint ldsw = (uint)w * 1024;        // wave-uniform LDS base (+lane*16 HW)

    // ds_read side: row R, byte (lg*16) ^ ((R>>1)&3)<<4; for R = base16+lr the
    // XOR term is the per-lane constant ((lr>>1)&3)<<4.
    const int kswz  = ((lr >> 1) & 3) << 4;
    const int aoff0 = (wrow * 64 + lr) * 64 + ((lg * 16) ^ kswz);
    const int boff0 = (wcol * 64 + lr) * 64 + ((lg * 16) ^ kswz);

#define STAGE_A(c, kt) do {                                                \
        const char* a0 = Ab + (kt) * 64;                                   \
        char* Ad = (char*)Als + (size_t)(c) * 8192 + ldsw;                 \
        GLL16(a0,                 Ad);                                     \
        GLL16(a0 + 64 * EDIM * 2, Ad + 4096);                              \
    } while (0)
#define STAGE_B(c, kt) do {                                                \
        const char* b0 = Bb + (kt) * 64;                                   \
        char* Bd = (char*)Bls + (size_t)(c) * 8192 + ldsw;                 \
        GLL16(b0,                 Bd);                                     \
        GLL16(b0 + 64 * EDIM * 2, Bd + 4096);                              \
    } while (0)

// Swapped operands: mfma(bv, av) -> acc[mi][ni][reg] =
//   C[mbase + mi*16 + lr][nbase + ni*16 + lg*4 + reg]
#define COMPUTE(ca, cb) do {                                               \
        const char* Ap = (const char*)Als + (size_t)(ca) * 8192;           \
        const char* Bp = (const char*)Bls + (size_t)(cb) * 8192;           \
        short8 av[4], bv[4];                                               \
        _Pragma("unroll")                                                  \
        for (int mi = 0; mi < 4; ++mi)                                     \
            av[mi] = *(const short8*)(Ap + aoff0 + mi * 1024);             \
        _Pragma("unroll")                                                  \
        for (int ni = 0; ni < 4; ++ni)                                     \
            bv[ni] = *(const short8*)(Bp + boff0 + ni * 1024);             \
        _Pragma("unroll")                                                  \
        for (int mi = 0; mi < 4; ++mi)                                     \
            _Pragma("unroll")                                              \
            for (int ni = 0; ni < 4; ++ni)                                 \
                acc[mi][ni] = __builtin_amdgcn_mfma_f32_16x16x32_bf16(     \
                    bv[ni], av[mi], acc[mi][ni], 0, 0, 0);                 \
    } while (0)

    // prologue: B(0), A(0), B(1) -> 6 loads in flight
    STAGE_B(0, 0);
    STAGE_A(0, 0);
    STAGE_B(1, 1);

    // main loop, iteration kt: stage A(kt+1) [1-step lead] and B(kt+2)
    // [2-step lead]; wait vmcnt(6) -> retires exactly B(kt),A(kt) (queue:
    // [B(kt),A(kt),B(kt+1),A(kt+1),B(kt+2)]); barrier; compute kt.
    // Overwrite targets were last read in COMPUTE(kt-1), protected by the
    // leading lgkm0+barrier.
    #pragma unroll
    for (int kt = 0; kt < 16; ++kt) {
        asm volatile("s_waitcnt lgkmcnt(0)" ::: "memory");
        __builtin_amdgcn_s_barrier();
        if (kt < 15) STAGE_A((kt + 1) & 1, kt + 1);
        if (kt < 14) STAGE_B((kt + 2) % 3, kt + 2);
        if (kt <= 13) {
            asm volatile("s_waitcnt vmcnt(6)" ::: "memory");
        } else if (kt == 14) {
            asm volatile("s_waitcnt vmcnt(4)" ::: "memory");
        } else {
            asm volatile("s_waitcnt vmcnt(0)" ::: "memory");
        }
        __builtin_amdgcn_s_barrier();
        COMPUTE(kt & 1, kt % 3);
    }

    // Epilogue: clamp + scale + fused ArcFace margin (rare branch: at most
    // one column per row carries the margin) + NT dwordx4 stores.
    // Fragment (mi,ni): lane lr is M-row mbase+mi*16+lr, regs are N-cols
    // nbase+ni*16+lg*4 .. +3. NCLS % 16 == 0 -> fragment-granular N guard.
    const int mbase = brow * 128 + wrow * 64;
    const int nbase = bcol * 128 + wcol * 64;
    #pragma unroll
    for (int mi = 0; mi < 4; ++mi) {
        const int grow = mbase + mi * 16 + lr;
        const int lab  = labels[grow];
        float* crow = C + (size_t)grow * NCLS;
        #pragma unroll
        for (int ni = 0; ni < 4; ++ni) {
            if (nbase + ni * 16 < NCLS) {
                const int c0 = nbase + ni * 16 + lg * 4;
                f32x4 v = acc[mi][ni];
                f32x4 o;
                #pragma unroll
                for (int j = 0; j < 4; ++j) {
                    float cc = fminf(fmaxf(v[j], -1.0f + 1e-7f), 1.0f - 1e-7f);
                    o[j] = cc * SCALE_;
                }
                const int d = lab - c0;
                if ((unsigned)d < 4u) {   // rare: this lane holds the label col
                    float cv = (d == 0) ? v[0] : (d == 1) ? v[1]
                             : (d == 2) ? v[2] : v[3];
                    float cc = fminf(fmaxf(cv, -1.0f + 1e-7f), 1.0f - 1e-7f);
                    float s  = sqrtf(1.0f - cc * cc);
                    float cm = cc * COS_M_ - s * SIN_M_;
                    cm = (cc > TH_) ? cm : (cc - MM_);
                    cm *= SCALE_;
                    #pragma unroll
                    for (int j = 0; j < 4; ++j)
                        o[j] = (d == j) ? cm : o[j];
                }
                __builtin_nontemporal_store(o, (f32x4*)&crow[c0]);
            }
        }
    }
#undef STAGE_A
#undef STAGE_B
#undef COMPUTE
}

extern "C" void kernel_launch(void* const* d_in, const int* in_sizes, int n_in,
                              void* d_out, int out_size, void* d_ws, size_t ws_size,
                              hipStream_t stream)
{
    const float* emb    = (const float*)d_in[0];
    const int*   labels = (const int*)d_in[1];
    const float* wgt    = (const float*)d_in[2];
    float*       out    = (float*)d_out;

    // workspace layout: [Ebf: 1024*512 bf16 = 1 MB][Wbf: 100096*512 bf16 = 102.5 MB]
    ushort* Ebf = (ushort*)d_ws;
    ushort* Wbf = (ushort*)((char*)d_ws + (size_t)BATCH * EDIM * 2);

    norm_all_kernel<<<(BATCH + NPAD) / 4, 256, 0, stream>>>(emb, wgt, Ebf, Wbf);

    gemm_arc_kernel<<<(BATCH / 128) * (NPAD / 128), 256, 0, stream>>>(Ebf, Wbf, labels, out);
}